// Round 14
// baseline (54.416 us; speedup 1.0000x reference)
//
#include <hip/hip_runtime.h>

// 4-level MoE routing loss, B=8, H=1024, ROUTE=64, 16x16 patches/level.
// d_in: out0, gt0, out1, gt1, out2, gt2, out3, gt3   (all fp32)
// d_out (fp32 flat): [0] loss | [1..8388609) label_patch (8,1024,1024)
//   | [+2048) moe_label as float | [+8192) score (8,4,16,16)
// ws: unused.
//
// R14 = exact R9 (best proven: 30.1us) with the 1-block loss_kernel
// replaced by FIRE-AND-FORGET float atomicAdd into d_out[0]:
//   - no return value -> no round-trip dependency (R4/R8's failure mode
//     was RETURNING atomics; R5 showed fire-and-forget atomics are cheap)
//   - d_out[0] zeroed per call by a 4-byte hipMemsetAsync (graph-legal;
//     replays re-zero, so accumulation is per-call deterministic up to
//     fp ordering ~1e-6 << 0.06 threshold)
//   - deletes the trailing dispatch + inter-dispatch gap (~3-5us tail)
// Kept: XCD row-swizzle, wave+LDS reduce, t0 section, 3/60/1 aligned-quad
// label stores (quads at lab[3+4j] = d_out byte%16==0 — PROVEN).
// Banned (falsified): returning hot-line atomics (R4/R8), device fences
// (R3), NT stores (R11), wave-per-patch (R10), unaligned dwordx4 (R12),
// LDS tile restaging (R13).

#define NPATCH 2048

__global__ __launch_bounds__(256) void fused_kernel(
    const float* __restrict__ out0, const float* __restrict__ gt0,
    const float* __restrict__ out1, const float* __restrict__ gt1,
    const float* __restrict__ out2, const float* __restrict__ gt2,
    const float* __restrict__ out3, const float* __restrict__ gt3,
    float* __restrict__ scoreOut,   // (B,4,16,16)
    float* __restrict__ moeF,       // moe_label as float
    float* __restrict__ lab,        // label_patch base (d_out+1)
    float* __restrict__ lossOut)    // d_out[0], pre-zeroed per call
{
    // XCD row-swizzle: all px of one (b,py) tile-row share an XCD.
    const int q = blockIdx.x;
    const int px = q >> 7;             // 0..15
    const int row = q & 127;           // b*16 + py
    const int b = row >> 4;
    const int py = row & 15;
    const int l = (py << 4) | px;
    const int p = (b << 8) | l;        // logical patch id

    const float* PO[4] = {out0, out1, out2, out3};
    const float* PG[4] = {gt0, gt1, gt2, gt3};

    float err[4], gts[4];

    #pragma unroll
    for (int lev = 0; lev < 4; ++lev) {
        const int k  = 64 >> lev;          // compile-time per unrolled iter
        const int W  = 1024 >> lev;
        const int kv = k >> 2;
        const int nvec = k * kv;
        const int rowBase = py * k, colBase = px * k;
        const size_t base = (size_t)b * W * W;
        const float* po = PO[lev];
        const float* pg = PG[lev];

        float e = 0.f, g = 0.f;
        for (int idx = threadIdx.x; idx < nvec; idx += 256) {
            int r = idx / kv;
            int c = (idx % kv) * 4;
            size_t off = base + (size_t)(rowBase + r) * W + (colBase + c);
            float4 o = *(const float4*)(po + off);
            float4 qv = *(const float4*)(pg + off);
            float dx = o.x - qv.x, dy = o.y - qv.y, dz = o.z - qv.z, dw = o.w - qv.w;
            e += dx * dx + dy * dy + dz * dz + dw * dw;
            g += qv.x + qv.y + qv.z + qv.w;
        }
        err[lev] = e; gts[lev] = g;
    }

    for (int s = 32; s; s >>= 1) {
        #pragma unroll
        for (int i = 0; i < 4; ++i) {
            err[i] += __shfl_down(err[i], s, 64);
            gts[i] += __shfl_down(gts[i], s, 64);
        }
    }
    __shared__ float se[4][4], sg[4][4];
    __shared__ int smv;
    const int wave = threadIdx.x >> 6, lane = threadIdx.x & 63;
    if (lane == 0) {
        #pragma unroll
        for (int i = 0; i < 4; ++i) { se[i][wave] = err[i]; sg[i][wave] = gts[i]; }
    }
    __syncthreads();
    if (threadIdx.x == 0) {
        float E[4], S[4];
        #pragma unroll
        for (int i = 0; i < 4; ++i) {
            E[i] = se[i][0] + se[i][1] + se[i][2] + se[i][3];
            float G = sg[i][0] + sg[i][1] + sg[i][2] + sg[i][3];
            float kk = (float)((64 >> i) * (64 >> i));
            S[i] = E[i] / kk + E[i] / (G + 1e-10f);
            scoreOut[b * 1024 + i * 256 + l] = S[i];
        }
        int m = 0; float best = S[0];
        #pragma unroll
        for (int i = 1; i < 4; ++i)
            if (S[i] < best) { best = S[i]; m = i; }   // strict <, first-min
        moeF[p] = (float)m;
        smv = m;
        double t = (double)E[0] / 8388608.0;
        if (m >= 1) t += (double)E[1] / 2097152.0;
        if (m >= 2) t += (double)E[2] / 524288.0;
        if (m >= 3) t += (double)E[3] / 131072.0;
        atomicAdd(lossOut, (float)t);      // fire-and-forget HW f32 atomic
    }
    __syncthreads();
    const int m = smv;

    // ---- phase 2: write own 64x64 label tile (R9 proven pattern) ----
    // Row y starts at lab index R0 (R0%4==0); d_out = lab+1 so the 16B-
    // aligned quads are lab[3+4j..6+4j], j=0..14; remainders lab[R0+0..2],
    // lab[R0+63].
    const size_t labBase = (size_t)b * 1048576 + (size_t)(py << 6) * 1024 + (px << 6);

    if (m == 0) {
        for (int idx = threadIdx.x; idx < 1024; idx += 256) {
            int y = idx >> 4, j = idx & 15;
            size_t R0 = labBase + (size_t)y * 1024;
            if (j < 15) {
                int x = 3 + 4 * j;
                float4 v;
                v.x = gt0[R0 + x];
                v.y = gt0[R0 + x + 1];
                v.z = gt0[R0 + x + 2];
                v.w = gt0[R0 + x + 3];
                *(float4*)(lab + R0 + x) = v;
            } else {
                lab[R0]      = gt0[R0];
                lab[R0 + 1]  = gt0[R0 + 1];
                lab[R0 + 2]  = gt0[R0 + 2];
                lab[R0 + 63] = gt0[R0 + 63];
            }
        }
    } else {
        const int k = 64 >> m, pad = (64 - k) >> 1, W = 1024 >> m;
        const float* gt = (m == 1) ? gt1 : (m == 2) ? gt2 : gt3;
        const size_t gbase = (size_t)b * W * W + (size_t)(py * k) * W + px * k;
        for (int idx = threadIdx.x; idx < 1024; idx += 256) {
            int y = idx >> 4, j = idx & 15;
            size_t R0 = labBase + (size_t)y * 1024;
            int iy = y - pad;
            bool rowIn = (unsigned)iy < (unsigned)k;
            const float* grow = gt + gbase + (size_t)iy * W;
            if (j < 15) {
                int x = 3 + 4 * j;
                float4 v;
                #pragma unroll
                for (int u = 0; u < 4; ++u) {
                    int ix = x + u - pad;
                    float vv = 0.2f;
                    if (rowIn && (unsigned)ix < (unsigned)k) vv = grow[ix];
                    ((float*)&v)[u] = vv;
                }
                *(float4*)(lab + R0 + x) = v;
            } else {
                #pragma unroll
                for (int u = 0; u < 3; ++u) {
                    int ix = u - pad;
                    float vv = 0.2f;
                    if (rowIn && (unsigned)ix < (unsigned)k) vv = grow[ix];
                    lab[R0 + u] = vv;
                }
                int ix = 63 - pad;
                float vv = 0.2f;
                if (rowIn && (unsigned)ix < (unsigned)k) vv = grow[ix];
                lab[R0 + 63] = vv;
            }
        }
    }
}

extern "C" void kernel_launch(void* const* d_in, const int* in_sizes, int n_in,
                              void* d_out, int out_size, void* d_ws, size_t ws_size,
                              hipStream_t stream) {
    const float* out0 = (const float*)d_in[0];
    const float* gt0  = (const float*)d_in[1];
    const float* out1 = (const float*)d_in[2];
    const float* gt1  = (const float*)d_in[3];
    const float* out2 = (const float*)d_in[4];
    const float* gt2  = (const float*)d_in[5];
    const float* out3 = (const float*)d_in[6];
    const float* gt3  = (const float*)d_in[7];

    float* o = (float*)d_out;
    float* lossOut  = o;
    float* labOut   = o + 1;
    float* moeFOut  = o + 8388609;
    float* scoreOut = o + 8390657;

    hipMemsetAsync(d_out, 0, 4, stream);   // zero loss accumulator (4 B)

    fused_kernel<<<NPATCH, 256, 0, stream>>>(
        out0, gt0, out1, gt1, out2, gt2, out3, gt3,
        scoreOut, moeFOut, labOut, lossOut);
}

// Round 15
// 33.135 us; speedup vs baseline: 1.6423x; 1.6423x over previous
//
#include <hip/hip_runtime.h>

// 4-level MoE routing loss, B=8, H=1024, ROUTE=64, 16x16 patches/level.
// d_in: out0, gt0, out1, gt1, out2, gt2, out3, gt3   (all fp32)
// d_out (fp32 flat): [0] loss | [1..8388609) label_patch (8,1024,1024)
//   | [+2048) moe_label as float | [+8192) score (8,4,16,16)
// ws: double lossTerm[2048] @0 (16KB), poisoned to 0xFF per call.
//
// R15 = exact R9 (best proven: 30.1us) + IN-GRID CONSUMER BLOCK:
//   block 0 (dispatched first, resident immediately) spin-reads the 2048
//   lossTerm slots with RELAXED AGENT-SCOPE loads until non-poison, then
//   reduces in loss_kernel's exact deterministic order and writes loss.
//   Producers publish via one relaxed agent-scope atomic STORE each
//   (write-through to shared L3; fire-and-forget; 2048 DISTINCT addresses;
//   no RMW, no fence, no wbl2, no hot line — avoids every falsified
//   mechanism: R3 fence, R4/R8 returning-hot-atomic, R14 hot-line f32 add).
//   Deletes the trailing loss dispatch + inter-dispatch gap.
// Kept: XCD row-swizzle (q-1 preserves it: 128%8==0), 3/60/1 aligned-quad
//   label stores (quads at lab[3+4j] = d_out byte%16==0 — PROVEN).
// Banned (falsified): hot-line atomics of ANY kind (R4/R8/R14), device
//   fences (R3), NT stores (R11), wave-per-patch (R10), unaligned dwordx4
//   (R12), LDS tile restage (R13).

#define NPATCH 2048
#define POISON 0xFFFFFFFFFFFFFFFFULL

__global__ __launch_bounds__(256) void fused_kernel(
    const float* __restrict__ out0, const float* __restrict__ gt0,
    const float* __restrict__ out1, const float* __restrict__ gt1,
    const float* __restrict__ out2, const float* __restrict__ gt2,
    const float* __restrict__ out3, const float* __restrict__ gt3,
    float* __restrict__ scoreOut,   // (B,4,16,16)
    float* __restrict__ moeF,       // moe_label as float
    float* __restrict__ lab,        // label_patch base (d_out+1)
    unsigned long long* __restrict__ lossTerm,  // ws, poisoned per call
    float* __restrict__ lossOut)    // d_out[0]
{
    const int t = threadIdx.x;

    // ---------------- consumer block ----------------
    if (blockIdx.x == 0) {
        unsigned long long vals[8];
        bool done[8] = {false, false, false, false, false, false, false, false};
        int remaining = 8;
        while (remaining) {
            #pragma unroll
            for (int z = 0; z < 8; ++z) {
                if (!done[z]) {
                    unsigned long long v = __hip_atomic_load(
                        &lossTerm[t + (z << 8)],
                        __ATOMIC_RELAXED, __HIP_MEMORY_SCOPE_AGENT);
                    if (v != POISON) { vals[z] = v; done[z] = true; --remaining; }
                }
            }
            if (remaining) __builtin_amdgcn_s_sleep(8);
        }
        // deterministic reduce: same order as the old loss_kernel
        double acc = 0.0;
        #pragma unroll
        for (int z = 0; z < 8; ++z) acc += __longlong_as_double((long long)vals[z]);
        for (int s = 32; s; s >>= 1) acc += __shfl_down(acc, s, 64);
        __shared__ double sd[4];
        const int wv = t >> 6, ln = t & 63;
        if (ln == 0) sd[wv] = acc;
        __syncthreads();
        if (t == 0) lossOut[0] = (float)(sd[0] + sd[1] + sd[2] + sd[3]);
        return;
    }

    // ---------------- producer blocks (exact R9 body) ----------------
    const int q = blockIdx.x - 1;      // 0..2047
    const int px = q >> 7;             // 0..15
    const int row = q & 127;           // b*16 + py  (XCD row-swizzle kept:
    const int b = row >> 4;            //  q%8 uniform across px of a row)
    const int py = row & 15;
    const int l = (py << 4) | px;
    const int p = (b << 8) | l;        // logical patch id

    const float* PO[4] = {out0, out1, out2, out3};
    const float* PG[4] = {gt0, gt1, gt2, gt3};

    float err[4], gts[4];

    #pragma unroll
    for (int lev = 0; lev < 4; ++lev) {
        const int k  = 64 >> lev;          // compile-time per unrolled iter
        const int W  = 1024 >> lev;
        const int kv = k >> 2;
        const int nvec = k * kv;
        const int rowBase = py * k, colBase = px * k;
        const size_t base = (size_t)b * W * W;
        const float* po = PO[lev];
        const float* pg = PG[lev];

        float e = 0.f, g = 0.f;
        for (int idx = t; idx < nvec; idx += 256) {
            int r = idx / kv;
            int c = (idx % kv) * 4;
            size_t off = base + (size_t)(rowBase + r) * W + (colBase + c);
            float4 o = *(const float4*)(po + off);
            float4 qv = *(const float4*)(pg + off);
            float dx = o.x - qv.x, dy = o.y - qv.y, dz = o.z - qv.z, dw = o.w - qv.w;
            e += dx * dx + dy * dy + dz * dz + dw * dw;
            g += qv.x + qv.y + qv.z + qv.w;
        }
        err[lev] = e; gts[lev] = g;
    }

    for (int s = 32; s; s >>= 1) {
        #pragma unroll
        for (int i = 0; i < 4; ++i) {
            err[i] += __shfl_down(err[i], s, 64);
            gts[i] += __shfl_down(gts[i], s, 64);
        }
    }
    __shared__ float se[4][4], sg[4][4];
    __shared__ int smv;
    const int wave = t >> 6, lane = t & 63;
    if (lane == 0) {
        #pragma unroll
        for (int i = 0; i < 4; ++i) { se[i][wave] = err[i]; sg[i][wave] = gts[i]; }
    }
    __syncthreads();
    if (t == 0) {
        float E[4], S[4];
        #pragma unroll
        for (int i = 0; i < 4; ++i) {
            E[i] = se[i][0] + se[i][1] + se[i][2] + se[i][3];
            float G = sg[i][0] + sg[i][1] + sg[i][2] + sg[i][3];
            float kk = (float)((64 >> i) * (64 >> i));
            S[i] = E[i] / kk + E[i] / (G + 1e-10f);
            scoreOut[b * 1024 + i * 256 + l] = S[i];
        }
        int m = 0; float best = S[0];
        #pragma unroll
        for (int i = 1; i < 4; ++i)
            if (S[i] < best) { best = S[i]; m = i; }   // strict <, first-min
        moeF[p] = (float)m;
        smv = m;
        double tt = (double)E[0] / 8388608.0;
        if (m >= 1) tt += (double)E[1] / 2097152.0;
        if (m >= 2) tt += (double)E[2] / 524288.0;
        if (m >= 3) tt += (double)E[3] / 131072.0;
        // publish: relaxed agent-scope store (write-through to shared L3)
        __hip_atomic_store(&lossTerm[p],
                           (unsigned long long)__double_as_longlong(tt),
                           __ATOMIC_RELAXED, __HIP_MEMORY_SCOPE_AGENT);
    }
    __syncthreads();
    const int m = smv;

    // ---- phase 2: write own 64x64 label tile (R9 proven pattern) ----
    const size_t labBase = (size_t)b * 1048576 + (size_t)(py << 6) * 1024 + (px << 6);

    if (m == 0) {
        for (int idx = t; idx < 1024; idx += 256) {
            int y = idx >> 4, j = idx & 15;
            size_t R0 = labBase + (size_t)y * 1024;
            if (j < 15) {
                int x = 3 + 4 * j;
                float4 v;
                v.x = gt0[R0 + x];
                v.y = gt0[R0 + x + 1];
                v.z = gt0[R0 + x + 2];
                v.w = gt0[R0 + x + 3];
                *(float4*)(lab + R0 + x) = v;
            } else {
                lab[R0]      = gt0[R0];
                lab[R0 + 1]  = gt0[R0 + 1];
                lab[R0 + 2]  = gt0[R0 + 2];
                lab[R0 + 63] = gt0[R0 + 63];
            }
        }
    } else {
        const int k = 64 >> m, pad = (64 - k) >> 1, W = 1024 >> m;
        const float* gt = (m == 1) ? gt1 : (m == 2) ? gt2 : gt3;
        const size_t gbase = (size_t)b * W * W + (size_t)(py * k) * W + px * k;
        for (int idx = t; idx < 1024; idx += 256) {
            int y = idx >> 4, j = idx & 15;
            size_t R0 = labBase + (size_t)y * 1024;
            int iy = y - pad;
            bool rowIn = (unsigned)iy < (unsigned)k;
            const float* grow = gt + gbase + (size_t)iy * W;
            if (j < 15) {
                int x = 3 + 4 * j;
                float4 v;
                #pragma unroll
                for (int u = 0; u < 4; ++u) {
                    int ix = x + u - pad;
                    float vv = 0.2f;
                    if (rowIn && (unsigned)ix < (unsigned)k) vv = grow[ix];
                    ((float*)&v)[u] = vv;
                }
                *(float4*)(lab + R0 + x) = v;
            } else {
                #pragma unroll
                for (int u = 0; u < 3; ++u) {
                    int ix = u - pad;
                    float vv = 0.2f;
                    if (rowIn && (unsigned)ix < (unsigned)k) vv = grow[ix];
                    lab[R0 + u] = vv;
                }
                int ix = 63 - pad;
                float vv = 0.2f;
                if (rowIn && (unsigned)ix < (unsigned)k) vv = grow[ix];
                lab[R0 + 63] = vv;
            }
        }
    }
}

extern "C" void kernel_launch(void* const* d_in, const int* in_sizes, int n_in,
                              void* d_out, int out_size, void* d_ws, size_t ws_size,
                              hipStream_t stream) {
    const float* out0 = (const float*)d_in[0];
    const float* gt0  = (const float*)d_in[1];
    const float* out1 = (const float*)d_in[2];
    const float* gt1  = (const float*)d_in[3];
    const float* out2 = (const float*)d_in[4];
    const float* gt2  = (const float*)d_in[5];
    const float* out3 = (const float*)d_in[6];
    const float* gt3  = (const float*)d_in[7];

    float* o = (float*)d_out;
    float* lossOut  = o;
    float* labOut   = o + 1;
    float* moeFOut  = o + 8388609;
    float* scoreOut = o + 8390657;

    unsigned long long* lossTerm = (unsigned long long*)d_ws;

    hipMemsetAsync(d_ws, 0xFF, NPATCH * 8, stream);   // poison slots per call

    fused_kernel<<<NPATCH + 1, 256, 0, stream>>>(
        out0, gt0, out1, gt1, out2, gt2, out3, gt3,
        scoreOut, moeFOut, labOut, lossTerm, lossOut);
}

// Round 16
// 31.187 us; speedup vs baseline: 1.7449x; 1.0625x over previous
//
#include <hip/hip_runtime.h>

// 4-level MoE routing loss, B=8, H=1024, ROUTE=64, 16x16 patches/level.
// d_in: out0, gt0, out1, gt1, out2, gt2, out3, gt3   (all fp32)
// d_out (fp32 flat): [0] loss | [1..8388609) label_patch (8,1024,1024)
//   | [+2048) moe_label as float | [+8192) score (8,4,16,16)
// ws: double lossTerm[2048] @0 (16KB).
//
// R16 = EXACT R9 REVERT (best proven: 30.1us). Final structure:
//   K1 fused (2048 blocks x 256): block p computes err/gt sums for all 4
//      pyramid levels of its patch (patch-local argmin!), scores, moe,
//      per-patch loss term (masked-MSE decomposes into per-patch err sums),
//      then writes its own 64x64 label tile (3/60/1 row split: 16B-aligned
//      quads at lab[3+4j] since lab = d_out+1; scalars for the remainder).
//      XCD row-swizzle: q -> (px = q>>7, row = q&127): all 16 px-adjacent
//      tiles of a tile-row share an XCD -> seam cachelines merge in its L2.
//   K2 loss (1 block): fixed-order deterministic reduce of 2048 doubles.
// Falsification ledger (do NOT revisit):
//   R3 device fence (wbl2/block) +60us | R4/R8 returning hot-line atomic
//   +14-24us | R14 fire-and-forget hot-line f32 atomic +24us | R15 in-grid
//   consumer +3us | R11 NT stores (break L2 write-merge) +9us | R12
//   unaligned dwordx4 stores CORRUPT | R13 LDS restage neutral (bank
//   conflicts) | R10 wave-per-patch -2.5us occupancy | R7 load batching
//   neutral | R5 linear-read 3-kernel split +16us.

#define NPATCH 2048

__global__ __launch_bounds__(256) void fused_kernel(
    const float* __restrict__ out0, const float* __restrict__ gt0,
    const float* __restrict__ out1, const float* __restrict__ gt1,
    const float* __restrict__ out2, const float* __restrict__ gt2,
    const float* __restrict__ out3, const float* __restrict__ gt3,
    float* __restrict__ scoreOut,   // (B,4,16,16)
    float* __restrict__ moeF,       // moe_label as float
    float* __restrict__ lab,        // label_patch base (d_out+1)
    double* __restrict__ lossTerm)  // ws [2048]
{
    // XCD row-swizzle: all px of one (b,py) tile-row share an XCD.
    const int q = blockIdx.x;
    const int px = q >> 7;             // 0..15
    const int row = q & 127;           // b*16 + py
    const int b = row >> 4;
    const int py = row & 15;
    const int l = (py << 4) | px;
    const int p = (b << 8) | l;        // logical patch id for moe/lossTerm

    const float* PO[4] = {out0, out1, out2, out3};
    const float* PG[4] = {gt0, gt1, gt2, gt3};

    float err[4], gts[4];

    #pragma unroll
    for (int lev = 0; lev < 4; ++lev) {
        const int k  = 64 >> lev;          // compile-time per unrolled iter
        const int W  = 1024 >> lev;
        const int kv = k >> 2;
        const int nvec = k * kv;
        const int rowBase = py * k, colBase = px * k;
        const size_t base = (size_t)b * W * W;
        const float* po = PO[lev];
        const float* pg = PG[lev];

        float e = 0.f, g = 0.f;
        for (int idx = threadIdx.x; idx < nvec; idx += 256) {
            int r = idx / kv;
            int c = (idx % kv) * 4;
            size_t off = base + (size_t)(rowBase + r) * W + (colBase + c);
            float4 o = *(const float4*)(po + off);
            float4 qv = *(const float4*)(pg + off);
            float dx = o.x - qv.x, dy = o.y - qv.y, dz = o.z - qv.z, dw = o.w - qv.w;
            e += dx * dx + dy * dy + dz * dz + dw * dw;
            g += qv.x + qv.y + qv.z + qv.w;
        }
        err[lev] = e; gts[lev] = g;
    }

    for (int s = 32; s; s >>= 1) {
        #pragma unroll
        for (int i = 0; i < 4; ++i) {
            err[i] += __shfl_down(err[i], s, 64);
            gts[i] += __shfl_down(gts[i], s, 64);
        }
    }
    __shared__ float se[4][4], sg[4][4];
    __shared__ int smv;
    const int wave = threadIdx.x >> 6, lane = threadIdx.x & 63;
    if (lane == 0) {
        #pragma unroll
        for (int i = 0; i < 4; ++i) { se[i][wave] = err[i]; sg[i][wave] = gts[i]; }
    }
    __syncthreads();
    if (threadIdx.x == 0) {
        float E[4], S[4];
        #pragma unroll
        for (int i = 0; i < 4; ++i) {
            E[i] = se[i][0] + se[i][1] + se[i][2] + se[i][3];
            float G = sg[i][0] + sg[i][1] + sg[i][2] + sg[i][3];
            float kk = (float)((64 >> i) * (64 >> i));
            S[i] = E[i] / kk + E[i] / (G + 1e-10f);
            scoreOut[b * 1024 + i * 256 + l] = S[i];
        }
        int m = 0; float best = S[0];
        #pragma unroll
        for (int i = 1; i < 4; ++i)
            if (S[i] < best) { best = S[i]; m = i; }   // strict <, first-min
        moeF[p] = (float)m;
        smv = m;
        double t = (double)E[0] / 8388608.0;
        if (m >= 1) t += (double)E[1] / 2097152.0;
        if (m >= 2) t += (double)E[2] / 524288.0;
        if (m >= 3) t += (double)E[3] / 131072.0;
        lossTerm[p] = t;
    }
    __syncthreads();
    const int m = smv;

    // ---- phase 2: write own 64x64 label tile, vectorized stores ----
    // lab row start R0 = labBase + y*1024 (R0 % 4 == 0); d_out = lab+1 so
    // aligned float4 slots are lab[3+4j .. 6+4j], j=0..14; remainders are
    // lab[R0+0..2] and lab[R0+63].
    const size_t labBase = (size_t)b * 1048576 + (size_t)(py << 6) * 1024 + (px << 6);

    if (m == 0) {
        for (int idx = threadIdx.x; idx < 1024; idx += 256) {
            int y = idx >> 4, j = idx & 15;
            size_t R0 = labBase + (size_t)y * 1024;
            if (j < 15) {
                int x = 3 + 4 * j;
                float4 v;
                v.x = gt0[R0 + x];
                v.y = gt0[R0 + x + 1];
                v.z = gt0[R0 + x + 2];
                v.w = gt0[R0 + x + 3];
                *(float4*)(lab + R0 + x) = v;
            } else {
                lab[R0]      = gt0[R0];
                lab[R0 + 1]  = gt0[R0 + 1];
                lab[R0 + 2]  = gt0[R0 + 2];
                lab[R0 + 63] = gt0[R0 + 63];
            }
        }
    } else {
        const int k = 64 >> m, pad = (64 - k) >> 1, W = 1024 >> m;
        const float* gt = (m == 1) ? gt1 : (m == 2) ? gt2 : gt3;
        const size_t gbase = (size_t)b * W * W + (size_t)(py * k) * W + px * k;
        for (int idx = threadIdx.x; idx < 1024; idx += 256) {
            int y = idx >> 4, j = idx & 15;
            size_t R0 = labBase + (size_t)y * 1024;
            int iy = y - pad;
            bool rowIn = (unsigned)iy < (unsigned)k;
            const float* grow = gt + gbase + (size_t)iy * W;
            if (j < 15) {
                int x = 3 + 4 * j;
                float4 v;
                #pragma unroll
                for (int u = 0; u < 4; ++u) {
                    int ix = x + u - pad;
                    float vv = 0.2f;
                    if (rowIn && (unsigned)ix < (unsigned)k) vv = grow[ix];
                    ((float*)&v)[u] = vv;
                }
                *(float4*)(lab + R0 + x) = v;
            } else {
                #pragma unroll
                for (int u = 0; u < 3; ++u) {
                    int ix = u - pad;
                    float vv = 0.2f;
                    if (rowIn && (unsigned)ix < (unsigned)k) vv = grow[ix];
                    lab[R0 + u] = vv;
                }
                int ix = 63 - pad;
                float vv = 0.2f;
                if (rowIn && (unsigned)ix < (unsigned)k) vv = grow[ix];
                lab[R0 + 63] = vv;
            }
        }
    }
}

__global__ __launch_bounds__(256) void loss_kernel(
    const double* __restrict__ lossTerm, float* __restrict__ lossOut)
{
    double t = 0.0;
    for (int i = threadIdx.x; i < NPATCH; i += 256) t += lossTerm[i];
    for (int s = 32; s; s >>= 1) t += __shfl_down(t, s, 64);
    __shared__ double sd[4];
    const int wave = threadIdx.x >> 6, lane = threadIdx.x & 63;
    if (lane == 0) sd[wave] = t;
    __syncthreads();
    if (threadIdx.x == 0)
        lossOut[0] = (float)(sd[0] + sd[1] + sd[2] + sd[3]);
}

extern "C" void kernel_launch(void* const* d_in, const int* in_sizes, int n_in,
                              void* d_out, int out_size, void* d_ws, size_t ws_size,
                              hipStream_t stream) {
    const float* out0 = (const float*)d_in[0];
    const float* gt0  = (const float*)d_in[1];
    const float* out1 = (const float*)d_in[2];
    const float* gt1  = (const float*)d_in[3];
    const float* out2 = (const float*)d_in[4];
    const float* gt2  = (const float*)d_in[5];
    const float* out3 = (const float*)d_in[6];
    const float* gt3  = (const float*)d_in[7];

    float* o = (float*)d_out;
    float* lossOut  = o;
    float* labOut   = o + 1;
    float* moeFOut  = o + 8388609;
    float* scoreOut = o + 8390657;

    double* lossTerm = (double*)d_ws;

    fused_kernel<<<NPATCH, 256, 0, stream>>>(
        out0, gt0, out1, gt1, out2, gt2, out3, gt3,
        scoreOut, moeFOut, labOut, lossTerm);
    loss_kernel<<<1, 256, 0, stream>>>(lossTerm, lossOut);
}